// Round 21
// baseline (104.453 us; speedup 1.0000x reference)
//
#include <hip/hip_runtime.h>

typedef unsigned long long u64;
typedef unsigned u32;

#define BATCH 16
#define Hh 512
#define Ww 512
#define IMG (Hh * Ww)          // 262144
#define TOT (BATCH * IMG)      // 4194304
#define WPI 4096               // words per image
#define WROW 8                 // words per row
#define NWORDS (TOT / 64)      // 65536
#define MIN_SIZE 262           // keep strictly greater
#define MAXRUNS (NWORDS * 32)  // 2M: id = word*32 + rank (deterministic)

#define BAND 8
#define HALO 5                 // 4 passes + 1 row so row r0+8 is locally valid
#define BROWS (BAND + 2 * HALO)     // 18
#define BWORDS (BROWS * WROW)       // 144
#define NBANDS (BATCH * 64)         // 1024

// run start within a word: nearest zero at-or-below set bit s, +1.
__device__ __forceinline__ u32 runstart(u64 bits, int s) {
    u64 ms = (s >= 63) ? ~0ULL : ((1ULL << (s + 1)) - 1);
    u64 nz = ~bits & ms;
    return nz ? (u32)(64 - __clzll(nz)) : 0u;
}
__device__ __forceinline__ u32 runlen(u64 bits, int s) {
    u64 v = ~(bits >> s);
    return v ? (u32)(__ffsll(v) - 1) : (u32)(64 - s);
}
// 0-based rank of the run containing set bit s (st = run-start mask)
__device__ __forceinline__ u32 runrank(u64 bits, u64 st, int s) {
    u32 rs = runstart(bits, s);
    return (u32)__popcll(st & (((u64)1 << rs) - 1));
}

__device__ __forceinline__ u64 morph_word(const u64* M, int w, int rr, bool er) {
    const u64 B = er ? ~0ULL : 0ULL;
    int wx = w & 7;
    u64 cc = M[w];
    u64 lf = (cc << 1) | (wx > 0 ? (M[w - 1] >> 63) : (er ? 1ULL : 0ULL));
    u64 rt = (cc >> 1) | (wx < 7 ? (M[w + 1] << 63) : (er ? (1ULL << 63) : 0ULL));
    u64 up = (rr <= 0)      ? B : (w >= WROW          ? M[w - WROW] : B);
    u64 dn = (rr >= Hh - 1) ? B : (w < BWORDS - WROW  ? M[w + WROW] : B);
    return er ? (cc & lf & rt & up & dn) : (cc | lf | rt | up | dn);
}

// ---------------- union-find primitives (LDS or global) ----------------
// ALL global-L mutations are uf_merge unions (atomicMin-retry) on an
// identity-initialized forest -> connectivity-preserving under any
// interleaving. (R20 lesson: a projection atomicMin DISCARDS edges.)
template <typename P>
__device__ __forceinline__ u32 uf_find_halve(P L, u32 x) {
    while (true) {
        u32 p = L[x];
        if (p == x) return x;
        u32 gp = L[p];
        if (gp == p) return p;
        atomicMin(&L[x], gp);   // halving: gp <= p < x, monotone-safe
        x = gp;
    }
}
template <typename P>
__device__ __forceinline__ void uf_merge(P L, u32 a, u32 b) {
    while (true) {
        a = uf_find_halve(L, a);
        b = uf_find_halve(L, b);
        if (a == b) return;
        if (a > b) { u32 t = a; a = b; b = t; }   // a < b
        u32 old = atomicMin(&L[b], a);
        if (old == b) return;
        b = old;
    }
}

// ========== vote + bitpack (2048 blocks) + L/counts init ==========
__global__ __launch_bounds__(256) void vote_pack_kernel(const float4* __restrict__ x4,
                                                        u64* __restrict__ mp0,
                                                        u32* __restrict__ L,
                                                        u32* __restrict__ counts) {
    int t = threadIdx.x, blk = blockIdx.x;
    // init: 2048*256 threads x 4 = exactly MAXRUNS entries each array
    u32 gidx = (u32)blk * 256 + t;
    ((uint4*)L)[gidx] = make_uint4(gidx * 4u, gidx * 4u + 1u, gidx * 4u + 2u, gidx * 4u + 3u);
    ((uint4*)counts)[gidx] = make_uint4(0u, 0u, 0u, 0u);

    int img = blk >> 7;                          // 128 blocks per image
    size_t p4 = (size_t)(blk & 127) * 512 + (size_t)t * 2;  // float4 idx in channel
    const float4* c1 = x4 + ((size_t)img * 4 + 1) * (IMG / 4);
    const float4* c2 = x4 + ((size_t)img * 4 + 2) * (IMG / 4);
    const float4* c3 = x4 + ((size_t)img * 4 + 3) * (IMG / 4);
    u32 m = 0;
    #pragma unroll
    for (int q = 0; q < 2; ++q) {
        float4 a1 = c1[p4 + q], a2 = c2[p4 + q], a3 = c3[p4 + q];
        u32 b0 = (a1.x > 0.5f) | ((a2.x > 0.5f) & (a3.x > 0.5f));
        u32 b1 = (a1.y > 0.5f) | ((a2.y > 0.5f) & (a3.y > 0.5f));
        u32 b2 = (a1.z > 0.5f) | ((a2.z > 0.5f) & (a3.z > 0.5f));
        u32 b3 = (a1.w > 0.5f) | ((a2.w > 0.5f) & (a3.w > 0.5f));
        m |= (b0 | (b1 << 1) | (b2 << 2) | (b3 << 3)) << (q * 4);
    }
    u32 a = m | (__shfl_xor(m, 1) << 8);                    // lanes %2==0: 16 px
    u32 b = a | (__shfl_xor(a, 2) << 16);                   // lanes %4==0: 32 px
    u64 w = (u64)b | ((u64)__shfl_xor(b, 4) << 32);         // lanes %8==0: 64 px
    if ((t & 7) == 0) mp0[(size_t)blk * 32 + (t >> 3)] = w;
}

// ========== morph (4 passes) + band CCL + OWN bottom-boundary merges =======
// ids are word-deterministic: id = global_word*32 + rank. With HALO=5 the
// morphed neighbor row r0+8 is locally computed bit-identical to the
// neighbor block's version (both windows cover the +-4 dependency cone),
// so cross-band unions need no communication.
__global__ __launch_bounds__(256) void morph_ccl_kernel(const u64* __restrict__ mp0,
                                                        u64* __restrict__ mp,
                                                        u32* __restrict__ L) {
    __shared__ u64 Ma[BWORDS], Mb[BWORDS];
    __shared__ u32 Ll[2048];            // 64 words x 32 ranks
    int blk = blockIdx.x;
    int img = blk >> 6;
    int r0  = (blk & 63) * BAND;
    int t = threadIdx.x;
    int rr = r0 - HALO + (t >> 3);

    if (t < BWORDS)
        Ma[t] = (rr >= 0 && rr < Hh) ? mp0[(size_t)img * WPI + (size_t)rr * WROW + (t & 7)] : 0;
    for (int i = t; i < 2048; i += 256) Ll[i] = (u32)i;
    __syncthreads();

    // close: D,E ; open: E,D   (A->B->A->B->A)
    if (t < BWORDS) Mb[t] = morph_word(Ma, t, rr, false);
    __syncthreads();
    if (t < BWORDS) Ma[t] = morph_word(Mb, t, rr, true);
    __syncthreads();
    if (t < BWORDS) Mb[t] = morph_word(Ma, t, rr, true);
    __syncthreads();
    if (t < BWORDS) Ma[t] = morph_word(Mb, t, rr, false);
    __syncthreads();

    const int OWN = HALO * WROW;        // 40: first owned word in Ma
    u32 gwbase = (u32)img * WPI + (u32)r0 * WROW;   // global word of local word 0
    if (t < 64)
        mp[(size_t)gwbase + t] = Ma[OWN + t];

    // ---- intra-band unions on local ids (lw*32 + rank) ----
    if (t < 56) {                       // vertical: rows (rp, rp+1), word w
        int rp = t >> 3, w = t & 7;
        u64 a = Ma[OWN + rp * 8 + w], b = Ma[OWN + (rp + 1) * 8 + w];
        u64 ov = a & b, seg = ov & ~(ov << 1);
        if (seg) {
            u64 sta = a & ~(a << 1), stb = b & ~(b << 1);
            u32 na = (u32)(rp * 8 + w) * 32, nb = (u32)((rp + 1) * 8 + w) * 32;
            while (seg) {
                int s = __ffsll(seg) - 1; seg &= seg - 1;
                uf_merge((u32*)Ll, na + runrank(a, sta, s), nb + runrank(b, stb, s));
            }
        }
    } else if (t >= 64 && t < 120) {    // horizontal: row r, words (w-1, w)
        int ht = t - 64;
        int r = ht / 7, w = 1 + ht % 7;
        u64 a = Ma[OWN + r * 8 + w - 1], b = Ma[OWN + r * 8 + w];
        if ((a >> 63) & b & 1ULL) {
            u64 sta = a & ~(a << 1);
            uf_merge((u32*)Ll, (u32)(r * 8 + w - 1) * 32 + runrank(a, sta, 63),
                               (u32)(r * 8 + w) * 32);      // bit0 run has rank 0
        }
    }
    __syncthreads();

    // ---- flatten: UNION each run with its band-root in global L ----
    // (must be a union, not a projection: neighbor blocks' boundary merges
    //  may have already lowered L[gid] — a projection would drop that edge)
    if (t < 64) {
        u64 bits = Ma[OWN + t];
        u64 st = bits & ~(bits << 1);
        u32 k = 0;
        while (st) {
            st &= st - 1;
            u32 lid = (u32)t * 32 + k;
            u32 r = lid, p = Ll[r];
            while (p != r) { r = p; p = Ll[r]; }   // read-only LDS chase
            u32 gid   = (gwbase + (u32)t) * 32 + k;
            u32 groot = (gwbase + (r >> 5)) * 32 + (r & 31);
            if (groot != gid) uf_merge(L, gid, groot);
            k++;
        }
    }

    // ---- bottom-boundary merges: rows r0+7 (owned) / r0+8 (halo-valid) ----
    if ((blk & 63) != 63 && t < 8) {
        u64 a = Ma[OWN + 56 + t];       // row 7, word t
        u64 b = Ma[OWN + 64 + t];       // row 8 (neighbor's row 0), word t
        u64 ov = a & b, seg = ov & ~(ov << 1);
        if (seg) {
            u64 sta = a & ~(a << 1), stb = b & ~(b << 1);
            u32 ga = (gwbase + 56 + (u32)t) * 32;
            u32 gb = (gwbase + 64 + (u32)t) * 32;
            while (seg) {
                int s = __ffsll(seg) - 1; seg &= seg - 1;
                uf_merge(L, ga + runrank(a, sta, s), gb + runrank(b, stb, s));
            }
        }
    }
}

// ========== accum: word sweep, wave-aggregated size accumulation ==========
__global__ __launch_bounds__(256) void accum_kernel(const u64* __restrict__ mp,
                                                    u32* __restrict__ L,
                                                    u32* __restrict__ counts) {
    int tid = threadIdx.x;
    int widx = blockIdx.x * 256 + tid;        // exact grid: NWORDS threads
    u64 bits = mp[widx];
    u64 st = bits & ~(bits << 1);
    u32 idb = (u32)widx * 32, k = 0;

    u32 r = 0, len = 0;
    bool pending = false;
    if (st) {
        int s = __ffsll(st) - 1; st &= st - 1;
        u32 id = idb + k; k++;
        u32 rr = id, p = L[rr];
        while (p != rr) { rr = p; p = L[rr]; }
        L[id] = rr;                            // own-slot compress (no writers now)
        r = rr; len = runlen(bits, s); pending = true;
    }
    while (true) {
        u64 act = __ballot(pending);
        if (!act) break;
        int leader = __ffsll(act) - 1;
        u32 lr = __shfl(r, leader);
        bool mine = pending && (r == lr);
        u32 c = mine ? len : 0u;
        c += __shfl_xor(c, 32); c += __shfl_xor(c, 16); c += __shfl_xor(c, 8);
        c += __shfl_xor(c, 4);  c += __shfl_xor(c, 2);  c += __shfl_xor(c, 1);
        if ((tid & 63) == leader) atomicAdd(&counts[lr], c);
        if (mine) {
            if (st) {
                int s = __ffsll(st) - 1; st &= st - 1;
                u32 id = idb + k; k++;
                u32 rr = id, p = L[rr];
                while (p != rr) { rr = p; p = L[rr]; }
                L[id] = rr;
                r = rr; len = runlen(bits, s);
            } else pending = false;
        }
    }
}

// ========== final: keep-mask per word (id = word*32+rank), float4 writes ===
__global__ __launch_bounds__(256) void final_kernel(const u64* __restrict__ mp,
                                                    const u32* __restrict__ L,
                                                    const u32* __restrict__ counts,
                                                    float* __restrict__ out) {
    __shared__ u64 km[128];
    int tid = threadIdx.x;
    if (tid < 128) {
        int widx = blockIdx.x * 128 + tid;
        u64 bits = mp[widx];
        u64 st = bits & ~(bits << 1);
        u32 id = (u32)widx * 32;
        u64 keep = 0;
        while (st) {
            int s = __ffsll(st) - 1; st &= st - 1;
            u32 r = L[id++];                  // exact root (accum compressed)
            if (counts[r] > MIN_SIZE) {
                u32 len = runlen(bits, s);
                keep |= (len == 64 ? ~0ULL : ((1ULL << len) - 1ULL)) << s;
            }
        }
        km[tid] = keep;
    }
    __syncthreads();
    float4* o4 = (float4*)out + (size_t)blockIdx.x * 2048;
    for (int i = tid; i < 2048; i += 256) {
        u32 nib = (u32)(km[i >> 4] >> ((i & 15) * 4)) & 0xFu;
        o4[i] = make_float4(nib & 1u ? 1.f : 0.f, nib & 2u ? 1.f : 0.f,
                            nib & 4u ? 1.f : 0.f, nib & 8u ? 1.f : 0.f);
    }
}

extern "C" void kernel_launch(void* const* d_in, const int* in_sizes, int n_in,
                              void* d_out, int out_size, void* d_ws, size_t ws_size,
                              hipStream_t stream) {
    const float* x = (const float*)d_in[0];
    float* out = (float*)d_out;

    // ws: mp0 .5MB | mp .5MB | L 8MB | counts 8MB   (~17MB)
    u64* mp0 = (u64*)d_ws;
    u64* mp  = mp0 + NWORDS;
    u32* L      = (u32*)(mp + NWORDS);
    u32* counts = L + MAXRUNS;

    const int block = 256;

    vote_pack_kernel<<<2048, block, 0, stream>>>((const float4*)x, mp0, L, counts);
    morph_ccl_kernel<<<NBANDS, block, 0, stream>>>(mp0, mp, L);
    accum_kernel<<<NWORDS / block, block, 0, stream>>>(mp, L, counts);
    final_kernel<<<512, block, 0, stream>>>(mp, L, counts, out);
}

// Round 22
// 76.958 us; speedup vs baseline: 1.3573x; 1.3573x over previous
//
#include <hip/hip_runtime.h>

typedef unsigned long long u64;
typedef unsigned u32;
typedef unsigned char u8;

#define BATCH 16
#define Hh 512
#define Ww 512
#define IMG (Hh * Ww)          // 262144
#define TOT (BATCH * IMG)      // 4194304
#define WPI 4096               // words per image
#define WROW 8                 // words per row
#define NWORDS (TOT / 64)      // 65536
#define MIN_SIZE 262           // keep strictly greater
#define MAXRUNS (NWORDS * 32)  // id-space cap (2M)

#define BAND 8
#define HALO 4
#define BROWS (BAND + 2 * HALO)     // 16
#define BWORDS (BROWS * WROW)       // 128
#define MAXBRUNS (64 * 32)          // 2048: max runs per band
#define NBANDS (BATCH * 64)         // 1024

// run start within a word: nearest zero at-or-below set bit s, +1.
__device__ __forceinline__ u32 runstart(u64 bits, int s) {
    u64 ms = (s >= 63) ? ~0ULL : ((1ULL << (s + 1)) - 1);
    u64 nz = ~bits & ms;
    return nz ? (u32)(64 - __clzll(nz)) : 0u;
}
__device__ __forceinline__ u32 runlen(u64 bits, int s) {
    u64 v = ~(bits >> s);
    return v ? (u32)(__ffsll(v) - 1) : (u32)(64 - s);
}
// rank of the run containing set bit s (st = run-start mask of the word)
__device__ __forceinline__ u32 runrank(u64 bits, u64 st, int s) {
    u32 rs = runstart(bits, s);
    return (u32)__popcll(st & (((u64)1 << rs) - 1));
}

__device__ __forceinline__ u64 morph_word(const u64* M, int w, int rr, bool er) {
    const u64 B = er ? ~0ULL : 0ULL;
    int wx = w & 7;
    u64 cc = M[w];
    u64 lf = (cc << 1) | (wx > 0 ? (M[w - 1] >> 63) : (er ? 1ULL : 0ULL));
    u64 rt = (cc >> 1) | (wx < 7 ? (M[w + 1] << 63) : (er ? (1ULL << 63) : 0ULL));
    u64 up = (rr <= 0)      ? B : (w >= WROW          ? M[w - WROW] : B);
    u64 dn = (rr >= Hh - 1) ? B : (w < BWORDS - WROW  ? M[w + WROW] : B);
    return er ? (cc & lf & rt & up & dn) : (cc | lf | rt | up | dn);
}

// ---------------- union-find primitives (LDS or global) ----------------
template <typename P>
__device__ __forceinline__ u32 uf_find_halve(P L, u32 x) {
    while (true) {
        u32 p = L[x];
        if (p == x) return x;
        u32 gp = L[p];
        if (gp == p) return p;
        atomicMin(&L[x], gp);   // halving: gp <= p < x, monotone-safe
        x = gp;
    }
}
template <typename P>
__device__ __forceinline__ void uf_merge(P L, u32 a, u32 b) {
    while (true) {
        a = uf_find_halve(L, a);
        b = uf_find_halve(L, b);
        if (a == b) return;
        if (a > b) { u32 t = a; a = b; b = t; }   // a < b
        u32 old = atomicMin(&L[b], a);
        if (old == b) return;
        b = old;
    }
}

// ========== vote + bitpack: 2048 blocks, 8 px/thread, 3-step shfl pack =====
__global__ __launch_bounds__(256) void vote_pack_kernel(const float4* __restrict__ x4,
                                                        u64* __restrict__ mp0,
                                                        u32* __restrict__ runCtr) {
    int t = threadIdx.x, blk = blockIdx.x;
    if (blk == 0 && t == 0) *runCtr = 0u;
    int img = blk >> 7;                          // 128 blocks per image
    size_t p4 = (size_t)(blk & 127) * 512 + (size_t)t * 2;  // float4 idx in channel
    const float4* c1 = x4 + ((size_t)img * 4 + 1) * (IMG / 4);
    const float4* c2 = x4 + ((size_t)img * 4 + 2) * (IMG / 4);
    const float4* c3 = x4 + ((size_t)img * 4 + 3) * (IMG / 4);
    u32 m = 0;
    #pragma unroll
    for (int q = 0; q < 2; ++q) {
        float4 a1 = c1[p4 + q], a2 = c2[p4 + q], a3 = c3[p4 + q];
        u32 b0 = (a1.x > 0.5f) | ((a2.x > 0.5f) & (a3.x > 0.5f));
        u32 b1 = (a1.y > 0.5f) | ((a2.y > 0.5f) & (a3.y > 0.5f));
        u32 b2 = (a1.z > 0.5f) | ((a2.z > 0.5f) & (a3.z > 0.5f));
        u32 b3 = (a1.w > 0.5f) | ((a2.w > 0.5f) & (a3.w > 0.5f));
        m |= (b0 | (b1 << 1) | (b2 << 2) | (b3 << 3)) << (q * 4);
    }
    u32 a = m | (__shfl_xor(m, 1) << 8);                    // lanes %2==0: 16 px
    u32 b = a | (__shfl_xor(a, 2) << 16);                   // lanes %4==0: 32 px
    u64 w = (u64)b | ((u64)__shfl_xor(b, 4) << 32);         // lanes %8==0: 64 px
    if ((t & 7) == 0) mp0[(size_t)blk * 32 + (t >> 3)] = w;
}

// ========== morph (4 passes) + band CCL on COMPACT RUN IDS ==========
__global__ __launch_bounds__(256) void morph_ccl_kernel(const u64* __restrict__ mp0,
                                                        u64* __restrict__ mp,
                                                        u32* __restrict__ L,
                                                        u32* __restrict__ wordbase,
                                                        u32* __restrict__ counts,
                                                        u8*  __restrict__ len8,
                                                        u32* __restrict__ runCtr) {
    __shared__ u64 Ma[BWORDS], Mb[BWORDS];
    __shared__ u32 Ll[MAXBRUNS];        // 8 KB
    __shared__ u32 wb_l[64];            // local (0-based) run base per owned word
    __shared__ u32 baseSh, totSh;
    int blk = blockIdx.x;
    int img = blk >> 6;
    int r0  = (blk & 63) * BAND;
    int t = threadIdx.x;
    int rr = r0 - HALO + (t >> 3);

    if (t < BWORDS)
        Ma[t] = (rr >= 0 && rr < Hh) ? mp0[(size_t)img * WPI + (size_t)rr * WROW + (t & 7)] : 0;
    __syncthreads();

    // close: D,E ; open: E,D
    if (t < BWORDS) Mb[t] = morph_word(Ma, t, rr, false);
    __syncthreads();
    if (t < BWORDS) Ma[t] = morph_word(Mb, t, rr, true);
    __syncthreads();
    if (t < BWORDS) Mb[t] = morph_word(Ma, t, rr, true);
    __syncthreads();
    if (t < BWORDS) Ma[t] = morph_word(Mb, t, rr, false);
    __syncthreads();

    if (t < 64)
        mp[(size_t)img * WPI + (size_t)r0 * WROW + t] = Ma[32 + t];

    // ---- run count + exclusive scan (wave 0) + global base ----
    u32 myexcl = 0;
    if (t < 64) {
        u64 bits = Ma[32 + t];
        u64 st = bits & ~(bits << 1);
        u32 cnt = __popcll(st);
        u32 inc = cnt;
        #pragma unroll
        for (int d = 1; d < 64; d <<= 1) {
            u32 v = __shfl_up(inc, d);
            if (t >= d) inc += v;
        }
        myexcl = inc - cnt;
        if (t == 63) { baseSh = atomicAdd(runCtr, inc); totSh = inc; }
    }
    __syncthreads();
    u32 base = baseSh, tot = totSh;
    if (t < 64) {
        wb_l[t] = myexcl;                                   // local base
        wordbase[(size_t)img * WPI + (size_t)r0 * WROW + t] = base + myexcl;
    }
    for (u32 i = t; i < tot; i += 256) { Ll[i] = i; counts[base + i] = 0u; }
    __syncthreads();

    // ---- unions on local run ids ----
    if (t < 56) {                       // vertical: rows (rp, rp+1), word w
        int rp = t >> 3, w = t & 7;
        u64 a = Ma[32 + rp * 8 + w], b = Ma[32 + (rp + 1) * 8 + w];
        u64 ov = a & b, seg = ov & ~(ov << 1);
        if (seg) {
            u64 sta = a & ~(a << 1), stb = b & ~(b << 1);
            u32 ba = wb_l[rp * 8 + w], bb = wb_l[(rp + 1) * 8 + w];
            while (seg) {
                int s = __ffsll(seg) - 1; seg &= seg - 1;
                uf_merge((u32*)Ll, ba + runrank(a, sta, s), bb + runrank(b, stb, s));
            }
        }
    } else if (t >= 64 && t < 120) {    // horizontal: row r, words (w-1, w)
        int ht = t - 64;
        int r = ht / 7, w = 1 + ht % 7;
        u64 a = Ma[32 + r * 8 + w - 1], b = Ma[32 + r * 8 + w];
        if ((a >> 63) & b & 1ULL) {
            u64 sta = a & ~(a << 1);
            uf_merge((u32*)Ll, wb_l[r * 8 + w - 1] + (u32)__popcll(sta & ~(1ULL << 63)) - 1u
                                 + (u32)((sta >> 63) & 1ULL),   // rank of run holding bit63
                               wb_l[r * 8 + w]);                // run at bit0 has rank 0
        }
    }
    __syncthreads();

    // ---- flatten + write L[id] = global root id, len8[id] ----
    if (t < 64) {
        u64 bits = Ma[32 + t];
        u64 st = bits & ~(bits << 1);
        u32 local = wb_l[t];
        while (st) {
            int s = __ffsll(st) - 1; st &= st - 1;
            u32 r = local, p = Ll[r];
            while (p != r) { r = p; p = Ll[r]; }       // read-only LDS chase
            L[base + local] = base + r;
            len8[base + local] = (u8)runlen(bits, s);
            local++;
        }
    }
}

// ========== cross-band boundary merges (compact ids) ==========
#define BITEMS (BATCH * 63 * WROW)    // 8064
__global__ void border_merge_kernel(const u64* __restrict__ mp,
                                    const u32* __restrict__ wordbase, u32* L) {
    int e = blockIdx.x * blockDim.x + threadIdx.x;
    if (e >= BITEMS) return;
    int w = e & 7, k = (e >> 3) % 63 + 1, img = e / (63 * 8);
    int R = k * BAND;                  // boundary rows R-1, R
    size_t wa_i = (size_t)img * WPI + (size_t)(R - 1) * WROW + w;
    size_t wb_i = (size_t)img * WPI + (size_t)R * WROW + w;
    u64 a = mp[wa_i], b = mp[wb_i];
    u64 ov = a & b, seg = ov & ~(ov << 1);
    if (!seg) return;
    u64 sta = a & ~(a << 1), stb = b & ~(b << 1);
    u32 wba = wordbase[wa_i], wbb = wordbase[wb_i];
    while (seg) {
        int s = __ffsll(seg) - 1; seg &= seg - 1;
        uf_merge(L, wba + runrank(a, sta, s), wbb + runrank(b, stb, s));
    }
}

// ========== accum: dense sweep over compact ids, wave-aggregated ==========
#define ACCUM_STRIDE (1024 * 256)
__global__ __launch_bounds__(256) void accum_kernel(u32* __restrict__ L,
                                                    const u8* __restrict__ len8,
                                                    u32* __restrict__ counts,
                                                    const u32* __restrict__ runCtr) {
    u32 n = *runCtr;
    u32 gid = blockIdx.x * 256 + threadIdx.x;
    int tid = threadIdx.x;
    u32 trips = (n + ACCUM_STRIDE - 1) / ACCUM_STRIDE;   // wave-uniform
    for (u32 k = 0; k < trips; ++k) {
        u32 id = gid + k * ACCUM_STRIDE;
        bool valid = id < n;
        u32 r = 0xFFFFFFFFu, len = 0;
        if (valid) {
            r = id; u32 p = L[r];
            while (p != r) { r = p; p = L[r]; }   // short: band-root + border hops
            L[id] = r;                             // own-slot compress for final
            len = len8[id];
        }
        bool pending = true;
        while (true) {
            u64 act = __ballot(pending);
            if (!act) break;
            int leader = __ffsll(act) - 1;
            u32 lr = __shfl(r, leader);
            bool mine = pending && (r == lr);
            u32 c = mine ? len : 0u;
            c += __shfl_xor(c, 32); c += __shfl_xor(c, 16); c += __shfl_xor(c, 8);
            c += __shfl_xor(c, 4);  c += __shfl_xor(c, 2);  c += __shfl_xor(c, 1);
            if ((tid & 63) == leader && lr != 0xFFFFFFFFu) atomicAdd(&counts[lr], c);
            if (mine) pending = false;
        }
    }
}

// ========== final: 512 blocks x 128 words, keep-mask + float4 writes =======
__global__ __launch_bounds__(256) void final_kernel(const u64* __restrict__ mp,
                                                    const u32* __restrict__ wordbase,
                                                    const u32* __restrict__ L,
                                                    const u32* __restrict__ counts,
                                                    float* __restrict__ out) {
    __shared__ u64 km[128];
    int tid = threadIdx.x;
    if (tid < 128) {
        int widx = blockIdx.x * 128 + tid;
        u64 bits = mp[widx];
        u64 st = bits & ~(bits << 1);
        u32 id = wordbase[widx];
        u64 keep = 0;
        while (st) {
            int s = __ffsll(st) - 1; st &= st - 1;
            u32 r = L[id++];                  // exact root (accum compressed)
            if (counts[r] > MIN_SIZE) {
                u32 len = runlen(bits, s);
                keep |= (len == 64 ? ~0ULL : ((1ULL << len) - 1ULL)) << s;
            }
        }
        km[tid] = keep;
    }
    __syncthreads();
    float4* o4 = (float4*)out + (size_t)blockIdx.x * 2048;
    for (int i = tid; i < 2048; i += 256) {
        u32 nib = (u32)(km[i >> 4] >> ((i & 15) * 4)) & 0xFu;
        o4[i] = make_float4(nib & 1u ? 1.f : 0.f, nib & 2u ? 1.f : 0.f,
                            nib & 4u ? 1.f : 0.f, nib & 8u ? 1.f : 0.f);
    }
}

extern "C" void kernel_launch(void* const* d_in, const int* in_sizes, int n_in,
                              void* d_out, int out_size, void* d_ws, size_t ws_size,
                              hipStream_t stream) {
    const float* x = (const float*)d_in[0];
    float* out = (float*)d_out;

    // ws: mp0 .5MB | mp .5MB | wordbase .25MB | L 8MB | counts 8MB | len8 2MB | runCtr
    u64* mp0 = (u64*)d_ws;
    u64* mp  = mp0 + NWORDS;
    u32* wordbase = (u32*)(mp + NWORDS);
    u32* L      = wordbase + NWORDS;
    u32* counts = L + MAXRUNS;
    u8*  len8   = (u8*)(counts + MAXRUNS);
    u32* runCtr = (u32*)(len8 + MAXRUNS);

    const int block = 256;

    vote_pack_kernel<<<2048, block, 0, stream>>>((const float4*)x, mp0, runCtr);
    morph_ccl_kernel<<<NBANDS, block, 0, stream>>>(mp0, mp, L, wordbase, counts, len8, runCtr);
    border_merge_kernel<<<(BITEMS + block - 1) / block, block, 0, stream>>>(mp, wordbase, L);
    accum_kernel<<<1024, block, 0, stream>>>(L, len8, counts, runCtr);
    final_kernel<<<512, block, 0, stream>>>(mp, wordbase, L, counts, out);
}